// Round 7
// baseline (931.969 us; speedup 1.0000x reference)
//
#include <hip/hip_runtime.h>
#include <hip/hip_bf16.h>

#define NVV 4096
#define NGG 2048
#define DD 64
#define KSP 128
#define NBLK 4
#define NEDGE 32768
#define COUT 8
#define NSLICE 8         // split-K for M=4096 GEMMs
#define NSLICE_G 16      // split-K for M=2048 rbf^T GEMM
#define VS 32            // spectral v-slices
#define AST 72           // LDS row stride in bf16 (144 B: 16B-aligned, 2-way banks)

typedef __hip_bfloat16 bf16;
using bf16x8 = __attribute__((ext_vector_type(8))) __bf16;
using s16x8  = __attribute__((ext_vector_type(8))) short;
using f32x4  = __attribute__((ext_vector_type(4))) float;

__device__ __forceinline__ float toF(bf16 x){ return __bfloat162float(x); }
// flag f: 1 = input buffers are bf16, 0 = f32 (runtime-probed)
__device__ __forceinline__ float ldin(const void* p, size_t i, int f){
  return f ? toF(((const bf16*)p)[i]) : ((const float*)p)[i];
}
__device__ __forceinline__ short f2bf(float x){
  __bf16 b = (__bf16)x;
  return __builtin_bit_cast(short, b);
}

// ---------------- dtype probe: mass ~ U[0.1,1) ----------------
__global__ void k_probe(const void* __restrict__ mass, int* __restrict__ flag){
  int t = threadIdx.x;                       // 64 threads
  float v = toF(((const bf16*)mass)[t]);
  bool ok = (v >= 0.05f) && (v <= 1.05f);
  unsigned long long m = __ballot(ok);
  if (t == 0) flag[0] = (m == ~0ull) ? 1 : 0;
}

// ---------------- one-time: flagged input -> bf16 (8 elems/thread) ----------
__global__ void k_cvt(const void* __restrict__ in, short* __restrict__ out,
                      const int* __restrict__ flg){
  const int f = *flg;
  size_t i0 = ((size_t)blockIdx.x*256 + threadIdx.x)*8;
  s16x8 v;
  if (f){
    v = *(const s16x8*)((const short*)in + i0);
  } else {
    const float* ip = (const float*)in + i0;
    float4 a0 = ((const float4*)ip)[0], a1 = ((const float4*)ip)[1];
    v[0]=f2bf(a0.x); v[1]=f2bf(a0.y); v[2]=f2bf(a0.z); v[3]=f2bf(a0.w);
    v[4]=f2bf(a1.x); v[5]=f2bf(a1.y); v[6]=f2bf(a1.z); v[7]=f2bf(a1.w);
  }
  *(s16x8*)(out + i0) = v;
}

// ---------------- one-time: rbf matrix [M x K] bf16, out[m][k]=exp(-|P_m-Q_k|/2.5)
__global__ void k_rbf_pre(const void* __restrict__ P, const void* __restrict__ Q,
                          short* __restrict__ out, int K, const int* __restrict__ flg){
  const int f = *flg;
  size_t i0 = ((size_t)blockIdx.x*256 + threadIdx.x)*8;   // 8 consecutive k, same m
  int m = (int)(i0 / K), k = (int)(i0 % K);
  float px = ldin(P, (size_t)m*3+0, f), py = ldin(P, (size_t)m*3+1, f), pz = ldin(P, (size_t)m*3+2, f);
  s16x8 v;
  #pragma unroll
  for (int j=0;j<8;j++){
    float dx = px - ldin(Q, (size_t)(k+j)*3+0, f);
    float dy = py - ldin(Q, (size_t)(k+j)*3+1, f);
    float dz = pz - ldin(Q, (size_t)(k+j)*3+2, f);
    v[j] = f2bf(__expf(-sqrtf(dx*dx+dy*dy+dz*dz)*0.4f));
  }
  *(s16x8*)(out + i0) = v;
}

// ---------------- input projection ----------------
__global__ void k_lin1(const void* __restrict__ sx, const void* __restrict__ w,
                       const void* __restrict__ b, float* __restrict__ out,
                       const int* __restrict__ flg){
  const int f = *flg;
  int idx = blockIdx.x*256 + threadIdx.x;    // NV*D
  int v = idx >> 6, d = idx & 63;
  float acc = ldin(b, d, f);
  #pragma unroll
  for (int k=0;k<5;k++) acc += ldin(sx, (size_t)v*5+k, f) * ldin(w, (size_t)k*DD+d, f);
  out[idx] = acc;
}

// ---- spectral partial ----
__global__ void k_spec_part(const void* __restrict__ evecs, const void* __restrict__ mass,
                            const float* __restrict__ x, float* __restrict__ partial,
                            const int* __restrict__ flg){
  const int f = *flg;
  __shared__ float red[4][DD];
  int k = blockIdx.x;            // 0..127
  int s = blockIdx.y;            // 0..VS-1
  int d = threadIdx.x & 63, g = threadIdx.x >> 6;
  int v0 = s*(NVV/VS);
  float acc = 0.f;
  for (int v = v0 + g; v < v0 + NVV/VS; v += 4){
    float em = ldin(evecs, (size_t)v*KSP + k, f) * ldin(mass, v, f);
    acc += em * x[(size_t)v*DD + d];
  }
  red[g][d] = acc;
  __syncthreads();
  if (threadIdx.x < DD)
    partial[((size_t)s*KSP + k)*DD + threadIdx.x] =
      red[0][threadIdx.x]+red[1][threadIdx.x]+red[2][threadIdx.x]+red[3][threadIdx.x];
}

// ---- spectral reduce + diffusion scale
__global__ void k_spec_red(const float* __restrict__ partial, const void* __restrict__ evals,
                           const void* __restrict__ tvec, int boff,
                           float* __restrict__ cs, const int* __restrict__ flg){
  const int f = *flg;
  int idx = blockIdx.x*256 + threadIdx.x;    // KSP*DD
  int k = idx >> 6, d = idx & 63;
  float sum = 0.f;
  #pragma unroll 8
  for (int s = 0; s < VS; s++) sum += partial[(size_t)s*KSP*DD + idx];
  float t = fmaxf(ldin(tvec, boff + d, f), 1e-8f);
  cs[idx] = expf(-ldin(evals, k, f) * t) * sum;
}

// ============ MFMA GEMM, N=64, flagged A (used for evecs @ cs) ==============
__global__ void k_gemm_mfma(const void* __restrict__ A, const float* __restrict__ B,
                            float* __restrict__ C, int M, int Kfull, int klen,
                            const int* __restrict__ flg){
  const int f = *flg;
  __shared__ __align__(16) short As[64*AST];   // As[m][k]
  __shared__ __align__(16) short Bs[64*AST];   // Bt[n][k]
  const int t = threadIdx.x;
  const int w = t>>6, lane = t&63;
  const int fr = lane&15, fq = lane>>4;
  const int mb = blockIdx.x*64;
  const int k0 = blockIdx.y*klen;
  const int sr = t>>2, sc = (t&3)*16;
  const int bk = t&63, bn = (t>>6)*16;
  f32x4 acc[4] = {{0,0,0,0},{0,0,0,0},{0,0,0,0},{0,0,0,0}};
  for (int kt=0; kt<klen; kt+=64){
    if (f==0){
      const float* Ap = (const float*)A + (size_t)(mb+sr)*Kfull + (k0+kt+sc);
      float4 a0 = ((const float4*)Ap)[0], a1 = ((const float4*)Ap)[1],
             a2 = ((const float4*)Ap)[2], a3 = ((const float4*)Ap)[3];
      s16x8 v0, v1;
      v0[0]=f2bf(a0.x); v0[1]=f2bf(a0.y); v0[2]=f2bf(a0.z); v0[3]=f2bf(a0.w);
      v0[4]=f2bf(a1.x); v0[5]=f2bf(a1.y); v0[6]=f2bf(a1.z); v0[7]=f2bf(a1.w);
      v1[0]=f2bf(a2.x); v1[1]=f2bf(a2.y); v1[2]=f2bf(a2.z); v1[3]=f2bf(a2.w);
      v1[4]=f2bf(a3.x); v1[5]=f2bf(a3.y); v1[6]=f2bf(a3.z); v1[7]=f2bf(a3.w);
      *(s16x8*)&As[sr*AST+sc]   = v0;
      *(s16x8*)&As[sr*AST+sc+8] = v1;
    } else {
      const short* Ap = (const short*)A + (size_t)(mb+sr)*Kfull + (k0+kt+sc);
      *(s16x8*)&As[sr*AST+sc]   = ((const s16x8*)Ap)[0];
      *(s16x8*)&As[sr*AST+sc+8] = ((const s16x8*)Ap)[1];
    }
    {
      const float* Bp = B + (size_t)(k0+kt+bk)*DD + bn;
      float bb[16];
      ((float4*)bb)[0] = ((const float4*)Bp)[0];
      ((float4*)bb)[1] = ((const float4*)Bp)[1];
      ((float4*)bb)[2] = ((const float4*)Bp)[2];
      ((float4*)bb)[3] = ((const float4*)Bp)[3];
      #pragma unroll
      for (int j=0;j<16;j++) Bs[(bn+j)*AST + bk] = f2bf(bb[j]);
    }
    __syncthreads();
    #pragma unroll
    for (int ks=0; ks<2; ks++){
      bf16x8 a = __builtin_bit_cast(bf16x8, *(const s16x8*)&As[(w*16+fr)*AST + ks*32 + fq*8]);
      #pragma unroll
      for (int nc=0;nc<4;nc++){
        bf16x8 b = __builtin_bit_cast(bf16x8, *(const s16x8*)&Bs[(nc*16+fr)*AST + ks*32 + fq*8]);
        acc[nc] = __builtin_amdgcn_mfma_f32_16x16x32_bf16(a, b, acc[nc], 0, 0, 0);
      }
    }
    __syncthreads();
  }
  float* Cp = C + (size_t)blockIdx.y * M * DD;
  const int row0 = mb + w*16 + fq*4;
  #pragma unroll
  for (int nc=0;nc<4;nc++)
    #pragma unroll
    for (int r=0;r<4;r++)
      Cp[(size_t)(row0+r)*DD + nc*16 + fr] = acc[nc][r];
}

// ============ MFMA GEMM, N=64, A pre-converted bf16 (rbf / rbfT) ============
__global__ void k_gemm_bf16(const short* __restrict__ A, const float* __restrict__ B,
                            float* __restrict__ C, int M, int Kfull, int klen){
  __shared__ __align__(16) short As[64*AST];
  __shared__ __align__(16) short Bs[64*AST];
  const int t = threadIdx.x;
  const int w = t>>6, lane = t&63;
  const int fr = lane&15, fq = lane>>4;
  const int mb = blockIdx.x*64;
  const int k0 = blockIdx.y*klen;
  const int sr = t>>2, sc = (t&3)*16;
  const int bk = t&63, bn = (t>>6)*16;
  f32x4 acc[4] = {{0,0,0,0},{0,0,0,0},{0,0,0,0},{0,0,0,0}};
  for (int kt=0; kt<klen; kt+=64){
    const short* Ap = A + (size_t)(mb+sr)*Kfull + (k0+kt+sc);
    *(s16x8*)&As[sr*AST+sc]   = ((const s16x8*)Ap)[0];
    *(s16x8*)&As[sr*AST+sc+8] = ((const s16x8*)Ap)[1];
    {
      const float* Bp = B + (size_t)(k0+kt+bk)*DD + bn;
      float bb[16];
      ((float4*)bb)[0] = ((const float4*)Bp)[0];
      ((float4*)bb)[1] = ((const float4*)Bp)[1];
      ((float4*)bb)[2] = ((const float4*)Bp)[2];
      ((float4*)bb)[3] = ((const float4*)Bp)[3];
      #pragma unroll
      for (int j=0;j<16;j++) Bs[(bn+j)*AST + bk] = f2bf(bb[j]);
    }
    __syncthreads();
    #pragma unroll
    for (int ks=0; ks<2; ks++){
      bf16x8 a = __builtin_bit_cast(bf16x8, *(const s16x8*)&As[(w*16+fr)*AST + ks*32 + fq*8]);
      #pragma unroll
      for (int nc=0;nc<4;nc++){
        bf16x8 b = __builtin_bit_cast(bf16x8, *(const s16x8*)&Bs[(nc*16+fr)*AST + ks*32 + fq*8]);
        acc[nc] = __builtin_amdgcn_mfma_f32_16x16x32_bf16(a, b, acc[nc], 0, 0, 0);
      }
    }
    __syncthreads();
  }
  float* Cp = C + (size_t)blockIdx.y * M * DD;
  const int row0 = mb + w*16 + fq*4;
  #pragma unroll
  for (int nc=0;nc<4;nc++)
    #pragma unroll
    for (int r=0;r<4;r++)
      Cp[(size_t)(row0+r)*DD + nc*16 + fr] = acc[nc][r];
}

// ============ merged gradX/gradY bf16 GEMM: grid.y 0..15 -> {X:0-7, Y:8-15} ==
__global__ void k_gemm_grad(const short* __restrict__ AX, const short* __restrict__ AY,
                            const float* __restrict__ B, float* __restrict__ C,
                            int klen){
  __shared__ __align__(16) short As[64*AST];
  __shared__ __align__(16) short Bs[64*AST];
  const int t = threadIdx.x;
  const int w = t>>6, lane = t&63;
  const int fr = lane&15, fq = lane>>4;
  const int mb = blockIdx.x*64;
  const int sl = blockIdx.y;
  const short* A = (sl < NSLICE) ? AX : AY;
  const int k0 = (sl & (NSLICE-1))*klen;
  const int sr = t>>2, sc = (t&3)*16;
  const int bk = t&63, bn = (t>>6)*16;
  f32x4 acc[4] = {{0,0,0,0},{0,0,0,0},{0,0,0,0},{0,0,0,0}};
  for (int kt=0; kt<klen; kt+=64){
    const short* Ap = A + (size_t)(mb+sr)*NVV + (k0+kt+sc);
    *(s16x8*)&As[sr*AST+sc]   = ((const s16x8*)Ap)[0];
    *(s16x8*)&As[sr*AST+sc+8] = ((const s16x8*)Ap)[1];
    {
      const float* Bp = B + (size_t)(k0+kt+bk)*DD + bn;
      float bb[16];
      ((float4*)bb)[0] = ((const float4*)Bp)[0];
      ((float4*)bb)[1] = ((const float4*)Bp)[1];
      ((float4*)bb)[2] = ((const float4*)Bp)[2];
      ((float4*)bb)[3] = ((const float4*)Bp)[3];
      #pragma unroll
      for (int j=0;j<16;j++) Bs[(bn+j)*AST + bk] = f2bf(bb[j]);
    }
    __syncthreads();
    #pragma unroll
    for (int ks=0; ks<2; ks++){
      bf16x8 a = __builtin_bit_cast(bf16x8, *(const s16x8*)&As[(w*16+fr)*AST + ks*32 + fq*8]);
      #pragma unroll
      for (int nc=0;nc<4;nc++){
        bf16x8 b = __builtin_bit_cast(bf16x8, *(const s16x8*)&Bs[(nc*16+fr)*AST + ks*32 + fq*8]);
        acc[nc] = __builtin_amdgcn_mfma_f32_16x16x32_bf16(a, b, acc[nc], 0, 0, 0);
      }
    }
    __syncthreads();
  }
  float* Cp = C + (size_t)sl * NVV * DD;
  const int row0 = mb + w*16 + fq*4;
  #pragma unroll
  for (int nc=0;nc<4;nc++)
    #pragma unroll
    for (int r=0;r<4;r++)
      Cp[(size_t)(row0+r)*DD + nc*16 + fr] = acc[nc][r];
}

__global__ void k_reduce(const float* __restrict__ P, float* __restrict__ C,
                         int M, int slices){
  int idx = blockIdx.x*256 + threadIdx.x;    // M*64
  float s = 0.f;
  for (int i=0;i<slices;i++) s += P[(size_t)i*M*DD + idx];
  C[idx] = s;
}

// ==== fused tail: gX/gY split-K sum + gfeat + 3-layer MLP + residual ========
__global__ void k_tail(const float* __restrict__ part, const float* __restrict__ cur,
                       const float* __restrict__ xdiff,
                       const void* __restrict__ Are, const void* __restrict__ Aim,
                       const void* __restrict__ w0, const void* __restrict__ b0,
                       const void* __restrict__ w1, const void* __restrict__ b1,
                       const void* __restrict__ w2, const void* __restrict__ b2,
                       int aoff, int w0off, int woff, int boff,
                       float* __restrict__ out, const int* __restrict__ flg){
  const int f = *flg;
  __shared__ float xs[4][DD], ys[4][DD];
  __shared__ float fs[4][3*DD];
  __shared__ float hs[4][DD];
  int d = threadIdx.x & 63, vl = threadIdx.x >> 6;
  size_t v = (size_t)blockIdx.x*4 + vl;
  float gx = 0.f, gy = 0.f;
  #pragma unroll
  for (int s = 0; s < NSLICE; s++){
    gx += part[(size_t)s*NVV*DD + v*DD + d];
    gy += part[(size_t)(s+NSLICE)*NVV*DD + v*DD + d];
  }
  xs[vl][d] = gx; ys[vl][d] = gy;
  fs[vl][d]      = cur[v*DD+d];
  fs[vl][DD+d]   = xdiff[v*DD+d];
  __syncthreads();
  float accre = 0.f, accim = 0.f;
  #pragma unroll 8
  for (int k=0;k<DD;k++){
    float ar = ldin(Are, (size_t)aoff + k*DD + d, f);
    float ai = ldin(Aim, (size_t)aoff + k*DD + d, f);
    float xr = xs[vl][k], yi = ys[vl][k];
    accre += xr*ar - yi*ai;
    accim += yi*ar + xr*ai;
  }
  fs[vl][2*DD+d] = tanhf(xs[vl][d]*accre + ys[vl][d]*accim);
  __syncthreads();
  float acc = ldin(b0, boff + d, f);
  #pragma unroll 8
  for (int k=0;k<3*DD;k++) acc += fs[vl][k]*ldin(w0, (size_t)w0off + k*DD + d, f);
  hs[vl][d] = fmaxf(acc, 0.f);
  __syncthreads();
  acc = ldin(b1, boff + d, f);
  #pragma unroll 8
  for (int k=0;k<DD;k++) acc += hs[vl][k]*ldin(w1, (size_t)woff + k*DD + d, f);
  float h1 = fmaxf(acc, 0.f);
  __syncthreads();
  hs[vl][d] = h1;
  __syncthreads();
  acc = ldin(b2, boff + d, f);
  #pragma unroll 8
  for (int k=0;k<DD;k++) acc += hs[vl][k]*ldin(w2, (size_t)woff + k*DD + d, f);
  out[v*DD+d] = acc + fs[vl][d];
}

// ==== GCN conv1: fold 16-slice partial sum + rowgemm + selfinit dual-write ==
__global__ void k_gcn1(const float* __restrict__ part, const void* __restrict__ W,
                       int woff, const float* __restrict__ dinv,
                       const void* __restrict__ bias, int boff,
                       float* __restrict__ tmp, float* __restrict__ outinit,
                       const int* __restrict__ flg){
  const int f = *flg;
  __shared__ float xs[4][DD];
  int d = threadIdx.x & 63, vl = threadIdx.x >> 6;
  size_t g = (size_t)blockIdx.x*4 + vl;
  float x = 0.f;
  #pragma unroll
  for (int s = 0; s < NSLICE_G; s++) x += part[(size_t)s*NGG*DD + g*DD + d];
  xs[vl][d] = x;
  __syncthreads();
  float acc = 0.f;
  #pragma unroll 8
  for (int k=0;k<DD;k++) acc += xs[vl][k]*ldin(W, (size_t)woff + k*DD + d, f);
  tmp[g*DD+d] = acc;
  float di = dinv[g];
  outinit[g*DD+d] = acc*di*di + ldin(bias, boff + d, f);
}

// ==== GCN conv2: relu(in) + rowgemm + selfinit dual-write ====
__global__ void k_gcn2(const float* __restrict__ X, const void* __restrict__ W,
                       int woff, const float* __restrict__ dinv,
                       const void* __restrict__ bias, int boff,
                       float* __restrict__ tmp, float* __restrict__ outinit,
                       const int* __restrict__ flg){
  const int f = *flg;
  __shared__ float xs[4][DD];
  int d = threadIdx.x & 63, vl = threadIdx.x >> 6;
  size_t g = (size_t)blockIdx.x*4 + vl;
  xs[vl][d] = fmaxf(X[g*DD+d], 0.f);
  __syncthreads();
  float acc = 0.f;
  #pragma unroll 8
  for (int k=0;k<DD;k++) acc += xs[vl][k]*ldin(W, (size_t)woff + k*DD + d, f);
  tmp[g*DD+d] = acc;
  float di = dinv[g];
  outinit[g*DD+d] = acc*di*di + ldin(bias, boff + d, f);
}

__global__ void k_scatter(const int* __restrict__ ei, const float* __restrict__ dinv,
                          const float* __restrict__ tmp, float* __restrict__ out){
  int idx = blockIdx.x*256 + threadIdx.x;    // NE*64
  int e = idx >> 6, d = idx & 63;
  int s = ei[e], t_ = ei[NEDGE + e];
  float w = dinv[s]*dinv[t_];
  atomicAdd(&out[(size_t)t_*DD + d], tmp[(size_t)s*DD + d]*w);
}

__global__ void k_deginit(float* deg){ int g = blockIdx.x*256+threadIdx.x; if (g<NGG) deg[g]=1.f; }
__global__ void k_degacc(const int* __restrict__ ei, float* deg){
  int e = blockIdx.x*256+threadIdx.x; if (e<NEDGE) atomicAdd(&deg[ei[NEDGE+e]], 1.f);
}
__global__ void k_dinv(float* deg){ int g = blockIdx.x*256+threadIdx.x; if (g<NGG) deg[g] = rsqrtf(deg[g]); }

// ---------------- final projection (dtype-flagged out) ----------------
__global__ void k_final(const float* __restrict__ x, const void* __restrict__ w,
                        const void* __restrict__ b, void* __restrict__ outv,
                        const int* __restrict__ flg){
  const int f = *flg;
  int idx = blockIdx.x*256 + threadIdx.x;    // NV*COUT
  int v = idx >> 3, c = idx & 7;
  float acc = ldin(b, c, f);
  #pragma unroll 8
  for (int k=0;k<DD;k++) acc += x[(size_t)v*DD+k]*ldin(w, (size_t)k*COUT+c, f);
  if (f) ((bf16*)outv)[idx] = __float2bfloat16(acc);
  else   ((float*)outv)[idx] = acc;
}

extern "C" void kernel_launch(void* const* d_in, const int* in_sizes, int n_in,
                              void* d_out, int out_size, void* d_ws, size_t ws_size,
                              hipStream_t stream){
  (void)in_sizes; (void)n_in;
  const void* surf_x   = d_in[0];
  const void* mass     = d_in[1];
  const void* evals    = d_in[2];
  const void* evecs    = d_in[3];
  const void* gradX    = d_in[4];
  const void* gradY    = d_in[5];
  const void* vertices = d_in[6];
  // d_in[7] graph_x, d_in[11] lin2_w, d_in[12] lin2_b are dead in the reference
  const void* gpos     = d_in[8];
  const void* lin1_w   = d_in[9];
  const void* lin1_b   = d_in[10];
  const void* last_w   = d_in[13];
  const void* last_b   = d_in[14];
  const void* dtime    = d_in[15];
  const void* A_re     = d_in[16];
  const void* A_im     = d_in[17];
  const void* mw0      = d_in[18];
  const void* mb0      = d_in[19];
  const void* mw1      = d_in[20];
  const void* mb1      = d_in[21];
  const void* mw2      = d_in[22];
  const void* mb2      = d_in[23];
  const void* gw1      = d_in[24];
  const void* gb1      = d_in[25];
  const void* gw2      = d_in[26];
  const void* gb2      = d_in[27];
  const int*  ei       = (const int*)d_in[28];

  // ---- workspace (~120 MB; measured ws_size ≈ 268 MB from harness fills)
  const size_t REQUIRED = (size_t)125*1024*1024;
  if (ws_size < REQUIRED){
    hipMemsetAsync(d_out, 0, (size_t)out_size*2, stream);
    return;
  }
  char* p = (char*)d_ws;
  auto alloc = [&](size_t bytes)->void*{
    void* r = (void*)p;
    p += (bytes + 255) & ~(size_t)255;
    return r;
  };
  short* gradXb = (short*)alloc((size_t)NVV*NVV*2);        // 32 MB
  short* gradYb = (short*)alloc((size_t)NVV*NVV*2);        // 32 MB
  short* rbfb   = (short*)alloc((size_t)NVV*NGG*2);        // 16 MB  [NV x NG]
  short* rbfTb  = (short*)alloc((size_t)NVV*NGG*2);        // 16 MB  [NG x NV]
  float* part  = (float*)alloc((size_t)2*NSLICE*NVV*DD*4); // 16 MB (16 slices max)
  float* bufA  = (float*)alloc((size_t)NVV*DD*4);          // 1 MB each
  float* bufB  = (float*)alloc((size_t)NVV*DD*4);
  float* xdiff = (float*)alloc((size_t)NVV*DD*4);
  float* tmpg  = (float*)alloc((size_t)NGG*DD*4);          // 0.5 MB each
  float* hg    = (float*)alloc((size_t)NGG*DD*4);
  float* tmp2  = (float*)alloc((size_t)NGG*DD*4);
  float* gx2   = (float*)alloc((size_t)NGG*DD*4);
  float* cs    = (float*)alloc((size_t)KSP*DD*4);
  float* dinv  = (float*)alloc((size_t)NGG*4);
  int*   flg   = (int*)alloc(256);

  // dtype probe first — everything downstream reads the flag
  k_probe<<<1, 64, 0, stream>>>(mass, flg);
  // one-time invariants: bf16 grads, bf16 rbf both layouts
  k_cvt<<<NVV*NVV/(256*8), 256, 0, stream>>>(gradX, gradXb, flg);
  k_cvt<<<NVV*NVV/(256*8), 256, 0, stream>>>(gradY, gradYb, flg);
  k_rbf_pre<<<NVV*NGG/(256*8), 256, 0, stream>>>(vertices, gpos, rbfb, NGG, flg);
  k_rbf_pre<<<NVV*NGG/(256*8), 256, 0, stream>>>(gpos, vertices, rbfTb, NVV, flg);
  k_deginit<<<NGG/256, 256, 0, stream>>>(dinv);
  k_degacc <<<NEDGE/256, 256, 0, stream>>>(ei, dinv);
  k_dinv   <<<NGG/256, 256, 0, stream>>>(dinv);
  k_lin1   <<<NVV*DD/256, 256, 0, stream>>>(surf_x, lin1_w, lin1_b, bufA, flg);

  float* cur = bufA;
  float* alt = bufB;
  for (int b = 0; b < NBLK; b++){
    // spectral projection + diffusion scale
    k_spec_part<<<dim3(KSP, VS), 256, 0, stream>>>(evecs, mass, cur, part, flg);
    k_spec_red<<<KSP*DD/256, 256, 0, stream>>>(part, evals, dtime, b*DD, cs, flg);
    // x_diff = evecs @ cs  (M=NV, K=128)
    k_gemm_mfma<<<dim3(NVV/64,1), 256, 0, stream>>>(evecs, cs, xdiff, NVV, KSP, KSP, flg);
    // gX | gY = {gradX,gradY} @ x_diff — one launch, 16 slices, bf16 A
    k_gemm_grad<<<dim3(NVV/64, 2*NSLICE), 256, 0, stream>>>(gradXb, gradYb, xdiff, part, NVV/NSLICE);
    // fused: split-K sums + gfeat + MLP + residual
    k_tail<<<NVV/4, 256, 0, stream>>>(part, cur, xdiff, A_re, A_im,
                                      mw0, mb0, mw1, mb1, mw2, mb2,
                                      b*DD*DD, b*3*DD*DD, b*DD*DD, b*DD, alt, flg);
    // gx = rbf^T @ mlp_out  (M=NG, K=NV), bf16 A
    k_gemm_bf16<<<dim3(NGG/64,NSLICE_G), 256, 0, stream>>>(rbfTb, alt, part, NGG, NVV, NVV/NSLICE_G);
    // GCN conv1: partial-sum + gemm + bias/dinv init, then edge scatter
    k_gcn1<<<NGG/4, 256, 0, stream>>>(part, gw1, b*DD*DD, dinv, gb1, b*DD, tmpg, hg, flg);
    k_scatter<<<NEDGE*DD/256, 256, 0, stream>>>(ei, dinv, tmpg, hg);
    // GCN conv2: relu + gemm + init, then scatter
    k_gcn2<<<NGG/4, 256, 0, stream>>>(hg, gw2, b*DD*DD, dinv, gb2, b*DD, tmp2, gx2, flg);
    k_scatter<<<NEDGE*DD/256, 256, 0, stream>>>(ei, dinv, tmp2, gx2);
    // diff_x = rbf @ gx2  (M=NV, K=NG), bf16 A
    k_gemm_bf16<<<dim3(NVV/64,NSLICE), 256, 0, stream>>>(rbfb, gx2, part, NVV, NGG, NGG/NSLICE);
    k_reduce<<<NVV*DD/256, 256, 0, stream>>>(part, cur, NVV, NSLICE);
  }
  k_final<<<NVV*COUT/256, 256, 0, stream>>>(cur, last_w, last_b, d_out, flg);
}

// Round 8
// 880.233 us; speedup vs baseline: 1.0588x; 1.0588x over previous
//
#include <hip/hip_runtime.h>
#include <hip/hip_bf16.h>

#define NVV 4096
#define NGG 2048
#define DD 64
#define KSP 128
#define NBLK 4
#define NEDGE 32768
#define COUT 8
#define NSLICE 8         // split-K for M=4096 GEMMs
#define NSLICE_G 16      // split-K for M=2048 rbf^T GEMM
#define VS 32            // spectral v-slices
#define AST 72           // LDS row stride in bf16 (144 B: 16B-aligned, 2-way banks)

typedef __hip_bfloat16 bf16;
using bf16x8 = __attribute__((ext_vector_type(8))) __bf16;
using s16x8  = __attribute__((ext_vector_type(8))) short;
using f32x4  = __attribute__((ext_vector_type(4))) float;

__device__ __forceinline__ float toF(bf16 x){ return __bfloat162float(x); }
// flag f: 1 = input buffers are bf16, 0 = f32 (runtime-probed)
__device__ __forceinline__ float ldin(const void* p, size_t i, int f){
  return f ? toF(((const bf16*)p)[i]) : ((const float*)p)[i];
}
__device__ __forceinline__ short f2bf(float x){
  __bf16 b = (__bf16)x;
  return __builtin_bit_cast(short, b);
}

// ---------------- dtype probe: mass ~ U[0.1,1) ----------------
__global__ void k_probe(const void* __restrict__ mass, int* __restrict__ flag){
  int t = threadIdx.x;                       // 64 threads
  float v = toF(((const bf16*)mass)[t]);
  bool ok = (v >= 0.05f) && (v <= 1.05f);
  unsigned long long m = __ballot(ok);
  if (t == 0) flag[0] = (m == ~0ull) ? 1 : 0;
}

// ---------------- one-time: flagged input -> bf16 (8 elems/thread) ----------
__global__ void k_cvt(const void* __restrict__ in, short* __restrict__ out,
                      const int* __restrict__ flg){
  const int f = *flg;
  size_t i0 = ((size_t)blockIdx.x*256 + threadIdx.x)*8;
  s16x8 v;
  if (f){
    v = *(const s16x8*)((const short*)in + i0);
  } else {
    const float* ip = (const float*)in + i0;
    float4 a0 = ((const float4*)ip)[0], a1 = ((const float4*)ip)[1];
    v[0]=f2bf(a0.x); v[1]=f2bf(a0.y); v[2]=f2bf(a0.z); v[3]=f2bf(a0.w);
    v[4]=f2bf(a1.x); v[5]=f2bf(a1.y); v[6]=f2bf(a1.z); v[7]=f2bf(a1.w);
  }
  *(s16x8*)(out + i0) = v;
}

// ---- one-time rbf [M x K] bf16: out[m][k]=exp(-|P_m-Q_k|/2.5), LDS-staged Q
// grid: (M, K/2048). Block = 256 thr; thread t handles k = t, t+256, ... (x8).
__global__ void k_rbf_pre(const void* __restrict__ P, const void* __restrict__ Q,
                          short* __restrict__ out, int K, const int* __restrict__ flg){
  const int f = *flg;
  __shared__ float Qx[2048], Qy[2048], Qz[2048];
  const int t = threadIdx.x;
  const int m = blockIdx.x;
  const int k0 = blockIdx.y*2048;
  for (int i = t; i < 2048; i += 256){
    Qx[i] = ldin(Q, (size_t)(k0+i)*3+0, f);
    Qy[i] = ldin(Q, (size_t)(k0+i)*3+1, f);
    Qz[i] = ldin(Q, (size_t)(k0+i)*3+2, f);
  }
  const float px = ldin(P, (size_t)m*3+0, f);
  const float py = ldin(P, (size_t)m*3+1, f);
  const float pz = ldin(P, (size_t)m*3+2, f);
  __syncthreads();
  short* op = out + (size_t)m*K + k0;
  #pragma unroll
  for (int j = 0; j < 8; j++){
    int i = t + j*256;
    float dx = px - Qx[i], dy = py - Qy[i], dz = pz - Qz[i];
    op[i] = f2bf(__expf(-sqrtf(dx*dx+dy*dy+dz*dz)*0.4f));
  }
}

// ---------------- input projection ----------------
__global__ void k_lin1(const void* __restrict__ sx, const void* __restrict__ w,
                       const void* __restrict__ b, float* __restrict__ out,
                       const int* __restrict__ flg){
  const int f = *flg;
  int idx = blockIdx.x*256 + threadIdx.x;    // NV*D
  int v = idx >> 6, d = idx & 63;
  float acc = ldin(b, d, f);
  #pragma unroll
  for (int k=0;k<5;k++) acc += ldin(sx, (size_t)v*5+k, f) * ldin(w, (size_t)k*DD+d, f);
  out[idx] = acc;
}

// ---- spectral partial ----
__global__ void k_spec_part(const void* __restrict__ evecs, const void* __restrict__ mass,
                            const float* __restrict__ x, float* __restrict__ partial,
                            const int* __restrict__ flg){
  const int f = *flg;
  __shared__ float red[4][DD];
  int k = blockIdx.x;            // 0..127
  int s = blockIdx.y;            // 0..VS-1
  int d = threadIdx.x & 63, g = threadIdx.x >> 6;
  int v0 = s*(NVV/VS);
  float acc = 0.f;
  for (int v = v0 + g; v < v0 + NVV/VS; v += 4){
    float em = ldin(evecs, (size_t)v*KSP + k, f) * ldin(mass, v, f);
    acc += em * x[(size_t)v*DD + d];
  }
  red[g][d] = acc;
  __syncthreads();
  if (threadIdx.x < DD)
    partial[((size_t)s*KSP + k)*DD + threadIdx.x] =
      red[0][threadIdx.x]+red[1][threadIdx.x]+red[2][threadIdx.x]+red[3][threadIdx.x];
}

// ---- spectral reduce + diffusion scale
__global__ void k_spec_red(const float* __restrict__ partial, const void* __restrict__ evals,
                           const void* __restrict__ tvec, int boff,
                           float* __restrict__ cs, const int* __restrict__ flg){
  const int f = *flg;
  int idx = blockIdx.x*256 + threadIdx.x;    // KSP*DD
  int k = idx >> 6, d = idx & 63;
  float sum = 0.f;
  #pragma unroll 8
  for (int s = 0; s < VS; s++) sum += partial[(size_t)s*KSP*DD + idx];
  float t = fmaxf(ldin(tvec, boff + d, f), 1e-8f);
  cs[idx] = expf(-ldin(evals, k, f) * t) * sum;
}

// ============ MFMA GEMM, N=64, flagged A (used for evecs @ cs) ==============
__global__ void k_gemm_mfma(const void* __restrict__ A, const float* __restrict__ B,
                            float* __restrict__ C, int M, int Kfull, int klen,
                            const int* __restrict__ flg){
  const int f = *flg;
  __shared__ __align__(16) short As[64*AST];   // As[m][k]
  __shared__ __align__(16) short Bs[64*AST];   // Bt[n][k]
  const int t = threadIdx.x;
  const int w = t>>6, lane = t&63;
  const int fr = lane&15, fq = lane>>4;
  const int mb = blockIdx.x*64;
  const int k0 = blockIdx.y*klen;
  const int sr = t>>2, sc = (t&3)*16;
  const int bk = t&63, bn = (t>>6)*16;
  f32x4 acc[4] = {{0,0,0,0},{0,0,0,0},{0,0,0,0},{0,0,0,0}};
  for (int kt=0; kt<klen; kt+=64){
    if (f==0){
      const float* Ap = (const float*)A + (size_t)(mb+sr)*Kfull + (k0+kt+sc);
      float4 a0 = ((const float4*)Ap)[0], a1 = ((const float4*)Ap)[1],
             a2 = ((const float4*)Ap)[2], a3 = ((const float4*)Ap)[3];
      s16x8 v0, v1;
      v0[0]=f2bf(a0.x); v0[1]=f2bf(a0.y); v0[2]=f2bf(a0.z); v0[3]=f2bf(a0.w);
      v0[4]=f2bf(a1.x); v0[5]=f2bf(a1.y); v0[6]=f2bf(a1.z); v0[7]=f2bf(a1.w);
      v1[0]=f2bf(a2.x); v1[1]=f2bf(a2.y); v1[2]=f2bf(a2.z); v1[3]=f2bf(a2.w);
      v1[4]=f2bf(a3.x); v1[5]=f2bf(a3.y); v1[6]=f2bf(a3.z); v1[7]=f2bf(a3.w);
      *(s16x8*)&As[sr*AST+sc]   = v0;
      *(s16x8*)&As[sr*AST+sc+8] = v1;
    } else {
      const short* Ap = (const short*)A + (size_t)(mb+sr)*Kfull + (k0+kt+sc);
      *(s16x8*)&As[sr*AST+sc]   = ((const s16x8*)Ap)[0];
      *(s16x8*)&As[sr*AST+sc+8] = ((const s16x8*)Ap)[1];
    }
    {
      const float* Bp = B + (size_t)(k0+kt+bk)*DD + bn;
      float bb[16];
      ((float4*)bb)[0] = ((const float4*)Bp)[0];
      ((float4*)bb)[1] = ((const float4*)Bp)[1];
      ((float4*)bb)[2] = ((const float4*)Bp)[2];
      ((float4*)bb)[3] = ((const float4*)Bp)[3];
      #pragma unroll
      for (int j=0;j<16;j++) Bs[(bn+j)*AST + bk] = f2bf(bb[j]);
    }
    __syncthreads();
    #pragma unroll
    for (int ks=0; ks<2; ks++){
      bf16x8 a = __builtin_bit_cast(bf16x8, *(const s16x8*)&As[(w*16+fr)*AST + ks*32 + fq*8]);
      #pragma unroll
      for (int nc=0;nc<4;nc++){
        bf16x8 b = __builtin_bit_cast(bf16x8, *(const s16x8*)&Bs[(nc*16+fr)*AST + ks*32 + fq*8]);
        acc[nc] = __builtin_amdgcn_mfma_f32_16x16x32_bf16(a, b, acc[nc], 0, 0, 0);
      }
    }
    __syncthreads();
  }
  float* Cp = C + (size_t)blockIdx.y * M * DD;
  const int row0 = mb + w*16 + fq*4;
  #pragma unroll
  for (int nc=0;nc<4;nc++)
    #pragma unroll
    for (int r=0;r<4;r++)
      Cp[(size_t)(row0+r)*DD + nc*16 + fr] = acc[nc][r];
}

// ============ MFMA GEMM, N=64, A pre-converted bf16 (rbf / rbfT) ============
__global__ void k_gemm_bf16(const short* __restrict__ A, const float* __restrict__ B,
                            float* __restrict__ C, int M, int Kfull, int klen){
  __shared__ __align__(16) short As[64*AST];
  __shared__ __align__(16) short Bs[64*AST];
  const int t = threadIdx.x;
  const int w = t>>6, lane = t&63;
  const int fr = lane&15, fq = lane>>4;
  const int mb = blockIdx.x*64;
  const int k0 = blockIdx.y*klen;
  const int sr = t>>2, sc = (t&3)*16;
  const int bk = t&63, bn = (t>>6)*16;
  f32x4 acc[4] = {{0,0,0,0},{0,0,0,0},{0,0,0,0},{0,0,0,0}};
  for (int kt=0; kt<klen; kt+=64){
    const short* Ap = A + (size_t)(mb+sr)*Kfull + (k0+kt+sc);
    *(s16x8*)&As[sr*AST+sc]   = ((const s16x8*)Ap)[0];
    *(s16x8*)&As[sr*AST+sc+8] = ((const s16x8*)Ap)[1];
    {
      const float* Bp = B + (size_t)(k0+kt+bk)*DD + bn;
      float bb[16];
      ((float4*)bb)[0] = ((const float4*)Bp)[0];
      ((float4*)bb)[1] = ((const float4*)Bp)[1];
      ((float4*)bb)[2] = ((const float4*)Bp)[2];
      ((float4*)bb)[3] = ((const float4*)Bp)[3];
      #pragma unroll
      for (int j=0;j<16;j++) Bs[(bn+j)*AST + bk] = f2bf(bb[j]);
    }
    __syncthreads();
    #pragma unroll
    for (int ks=0; ks<2; ks++){
      bf16x8 a = __builtin_bit_cast(bf16x8, *(const s16x8*)&As[(w*16+fr)*AST + ks*32 + fq*8]);
      #pragma unroll
      for (int nc=0;nc<4;nc++){
        bf16x8 b = __builtin_bit_cast(bf16x8, *(const s16x8*)&Bs[(nc*16+fr)*AST + ks*32 + fq*8]);
        acc[nc] = __builtin_amdgcn_mfma_f32_16x16x32_bf16(a, b, acc[nc], 0, 0, 0);
      }
    }
    __syncthreads();
  }
  float* Cp = C + (size_t)blockIdx.y * M * DD;
  const int row0 = mb + w*16 + fq*4;
  #pragma unroll
  for (int nc=0;nc<4;nc++)
    #pragma unroll
    for (int r=0;r<4;r++)
      Cp[(size_t)(row0+r)*DD + nc*16 + fr] = acc[nc][r];
}

// ============ merged gradX/gradY bf16 GEMM: grid.y 0..15 -> {X:0-7, Y:8-15} ==
__global__ void k_gemm_grad(const short* __restrict__ AX, const short* __restrict__ AY,
                            const float* __restrict__ B, float* __restrict__ C,
                            int klen){
  __shared__ __align__(16) short As[64*AST];
  __shared__ __align__(16) short Bs[64*AST];
  const int t = threadIdx.x;
  const int w = t>>6, lane = t&63;
  const int fr = lane&15, fq = lane>>4;
  const int mb = blockIdx.x*64;
  const int sl = blockIdx.y;
  const short* A = (sl < NSLICE) ? AX : AY;
  const int k0 = (sl & (NSLICE-1))*klen;
  const int sr = t>>2, sc = (t&3)*16;
  const int bk = t&63, bn = (t>>6)*16;
  f32x4 acc[4] = {{0,0,0,0},{0,0,0,0},{0,0,0,0},{0,0,0,0}};
  for (int kt=0; kt<klen; kt+=64){
    const short* Ap = A + (size_t)(mb+sr)*NVV + (k0+kt+sc);
    *(s16x8*)&As[sr*AST+sc]   = ((const s16x8*)Ap)[0];
    *(s16x8*)&As[sr*AST+sc+8] = ((const s16x8*)Ap)[1];
    {
      const float* Bp = B + (size_t)(k0+kt+bk)*DD + bn;
      float bb[16];
      ((float4*)bb)[0] = ((const float4*)Bp)[0];
      ((float4*)bb)[1] = ((const float4*)Bp)[1];
      ((float4*)bb)[2] = ((const float4*)Bp)[2];
      ((float4*)bb)[3] = ((const float4*)Bp)[3];
      #pragma unroll
      for (int j=0;j<16;j++) Bs[(bn+j)*AST + bk] = f2bf(bb[j]);
    }
    __syncthreads();
    #pragma unroll
    for (int ks=0; ks<2; ks++){
      bf16x8 a = __builtin_bit_cast(bf16x8, *(const s16x8*)&As[(w*16+fr)*AST + ks*32 + fq*8]);
      #pragma unroll
      for (int nc=0;nc<4;nc++){
        bf16x8 b = __builtin_bit_cast(bf16x8, *(const s16x8*)&Bs[(nc*16+fr)*AST + ks*32 + fq*8]);
        acc[nc] = __builtin_amdgcn_mfma_f32_16x16x32_bf16(a, b, acc[nc], 0, 0, 0);
      }
    }
    __syncthreads();
  }
  float* Cp = C + (size_t)sl * NVV * DD;
  const int row0 = mb + w*16 + fq*4;
  #pragma unroll
  for (int nc=0;nc<4;nc++)
    #pragma unroll
    for (int r=0;r<4;r++)
      Cp[(size_t)(row0+r)*DD + nc*16 + fr] = acc[nc][r];
}

__global__ void k_reduce(const float* __restrict__ P, float* __restrict__ C,
                         int M, int slices){
  int idx = blockIdx.x*256 + threadIdx.x;    // M*64
  float s = 0.f;
  for (int i=0;i<slices;i++) s += P[(size_t)i*M*DD + idx];
  C[idx] = s;
}

// ==== fused tail: gX/gY split-K sum + gfeat + 3-layer MLP + residual ========
__global__ void k_tail(const float* __restrict__ part, const float* __restrict__ cur,
                       const float* __restrict__ xdiff,
                       const void* __restrict__ Are, const void* __restrict__ Aim,
                       const void* __restrict__ w0, const void* __restrict__ b0,
                       const void* __restrict__ w1, const void* __restrict__ b1,
                       const void* __restrict__ w2, const void* __restrict__ b2,
                       int aoff, int w0off, int woff, int boff,
                       float* __restrict__ out, const int* __restrict__ flg){
  const int f = *flg;
  __shared__ float xs[4][DD], ys[4][DD];
  __shared__ float fs[4][3*DD];
  __shared__ float hs[4][DD];
  int d = threadIdx.x & 63, vl = threadIdx.x >> 6;
  size_t v = (size_t)blockIdx.x*4 + vl;
  float gx = 0.f, gy = 0.f;
  #pragma unroll
  for (int s = 0; s < NSLICE; s++){
    gx += part[(size_t)s*NVV*DD + v*DD + d];
    gy += part[(size_t)(s+NSLICE)*NVV*DD + v*DD + d];
  }
  xs[vl][d] = gx; ys[vl][d] = gy;
  fs[vl][d]      = cur[v*DD+d];
  fs[vl][DD+d]   = xdiff[v*DD+d];
  __syncthreads();
  float accre = 0.f, accim = 0.f;
  #pragma unroll 8
  for (int k=0;k<DD;k++){
    float ar = ldin(Are, (size_t)aoff + k*DD + d, f);
    float ai = ldin(Aim, (size_t)aoff + k*DD + d, f);
    float xr = xs[vl][k], yi = ys[vl][k];
    accre += xr*ar - yi*ai;
    accim += yi*ar + xr*ai;
  }
  fs[vl][2*DD+d] = tanhf(xs[vl][d]*accre + ys[vl][d]*accim);
  __syncthreads();
  float acc = ldin(b0, boff + d, f);
  #pragma unroll 8
  for (int k=0;k<3*DD;k++) acc += fs[vl][k]*ldin(w0, (size_t)w0off + k*DD + d, f);
  hs[vl][d] = fmaxf(acc, 0.f);
  __syncthreads();
  acc = ldin(b1, boff + d, f);
  #pragma unroll 8
  for (int k=0;k<DD;k++) acc += hs[vl][k]*ldin(w1, (size_t)woff + k*DD + d, f);
  float h1 = fmaxf(acc, 0.f);
  __syncthreads();
  hs[vl][d] = h1;
  __syncthreads();
  acc = ldin(b2, boff + d, f);
  #pragma unroll 8
  for (int k=0;k<DD;k++) acc += hs[vl][k]*ldin(w2, (size_t)woff + k*DD + d, f);
  out[v*DD+d] = acc + fs[vl][d];
}

// ==== GCN conv1: fold 16-slice partial sum + rowgemm + selfinit dual-write ==
__global__ void k_gcn1(const float* __restrict__ part, const void* __restrict__ W,
                       int woff, const float* __restrict__ dinv,
                       const void* __restrict__ bias, int boff,
                       float* __restrict__ tmp, float* __restrict__ outinit,
                       const int* __restrict__ flg){
  const int f = *flg;
  __shared__ float xs[4][DD];
  int d = threadIdx.x & 63, vl = threadIdx.x >> 6;
  size_t g = (size_t)blockIdx.x*4 + vl;
  float x = 0.f;
  #pragma unroll
  for (int s = 0; s < NSLICE_G; s++) x += part[(size_t)s*NGG*DD + g*DD + d];
  xs[vl][d] = x;
  __syncthreads();
  float acc = 0.f;
  #pragma unroll 8
  for (int k=0;k<DD;k++) acc += xs[vl][k]*ldin(W, (size_t)woff + k*DD + d, f);
  tmp[g*DD+d] = acc;
  float di = dinv[g];
  outinit[g*DD+d] = acc*di*di + ldin(bias, boff + d, f);
}

// ==== GCN conv2: relu(in) + rowgemm + selfinit dual-write ====
__global__ void k_gcn2(const float* __restrict__ X, const void* __restrict__ W,
                       int woff, const float* __restrict__ dinv,
                       const void* __restrict__ bias, int boff,
                       float* __restrict__ tmp, float* __restrict__ outinit,
                       const int* __restrict__ flg){
  const int f = *flg;
  __shared__ float xs[4][DD];
  int d = threadIdx.x & 63, vl = threadIdx.x >> 6;
  size_t g = (size_t)blockIdx.x*4 + vl;
  xs[vl][d] = fmaxf(X[g*DD+d], 0.f);
  __syncthreads();
  float acc = 0.f;
  #pragma unroll 8
  for (int k=0;k<DD;k++) acc += xs[vl][k]*ldin(W, (size_t)woff + k*DD + d, f);
  tmp[g*DD+d] = acc;
  float di = dinv[g];
  outinit[g*DD+d] = acc*di*di + ldin(bias, boff + d, f);
}

__global__ void k_scatter(const int* __restrict__ ei, const float* __restrict__ dinv,
                          const float* __restrict__ tmp, float* __restrict__ out){
  int idx = blockIdx.x*256 + threadIdx.x;    // NE*64
  int e = idx >> 6, d = idx & 63;
  int s = ei[e], t_ = ei[NEDGE + e];
  float w = dinv[s]*dinv[t_];
  atomicAdd(&out[(size_t)t_*DD + d], tmp[(size_t)s*DD + d]*w);
}

__global__ void k_deginit(float* deg){ int g = blockIdx.x*256+threadIdx.x; if (g<NGG) deg[g]=1.f; }
__global__ void k_degacc(const int* __restrict__ ei, float* deg){
  int e = blockIdx.x*256+threadIdx.x; if (e<NEDGE) atomicAdd(&deg[ei[NEDGE+e]], 1.f);
}
__global__ void k_dinv(float* deg){ int g = blockIdx.x*256+threadIdx.x; if (g<NGG) deg[g] = rsqrtf(deg[g]); }

// ---------------- final projection (dtype-flagged out) ----------------
__global__ void k_final(const float* __restrict__ x, const void* __restrict__ w,
                        const void* __restrict__ b, void* __restrict__ outv,
                        const int* __restrict__ flg){
  const int f = *flg;
  int idx = blockIdx.x*256 + threadIdx.x;    // NV*COUT
  int v = idx >> 3, c = idx & 7;
  float acc = ldin(b, c, f);
  #pragma unroll 8
  for (int k=0;k<DD;k++) acc += x[(size_t)v*DD+k]*ldin(w, (size_t)k*COUT+c, f);
  if (f) ((bf16*)outv)[idx] = __float2bfloat16(acc);
  else   ((float*)outv)[idx] = acc;
}

extern "C" void kernel_launch(void* const* d_in, const int* in_sizes, int n_in,
                              void* d_out, int out_size, void* d_ws, size_t ws_size,
                              hipStream_t stream){
  (void)in_sizes; (void)n_in;
  const void* surf_x   = d_in[0];
  const void* mass     = d_in[1];
  const void* evals    = d_in[2];
  const void* evecs    = d_in[3];
  const void* gradX    = d_in[4];
  const void* gradY    = d_in[5];
  const void* vertices = d_in[6];
  // d_in[7] graph_x, d_in[11] lin2_w, d_in[12] lin2_b are dead in the reference
  const void* gpos     = d_in[8];
  const void* lin1_w   = d_in[9];
  const void* lin1_b   = d_in[10];
  const void* last_w   = d_in[13];
  const void* last_b   = d_in[14];
  const void* dtime    = d_in[15];
  const void* A_re     = d_in[16];
  const void* A_im     = d_in[17];
  const void* mw0      = d_in[18];
  const void* mb0      = d_in[19];
  const void* mw1      = d_in[20];
  const void* mb1      = d_in[21];
  const void* mw2      = d_in[22];
  const void* mb2      = d_in[23];
  const void* gw1      = d_in[24];
  const void* gb1      = d_in[25];
  const void* gw2      = d_in[26];
  const void* gb2      = d_in[27];
  const int*  ei       = (const int*)d_in[28];

  // ---- workspace (~120 MB; measured ws_size ≈ 268 MB from harness fills)
  const size_t REQUIRED = (size_t)125*1024*1024;
  if (ws_size < REQUIRED){
    hipMemsetAsync(d_out, 0, (size_t)out_size*2, stream);
    return;
  }
  char* p = (char*)d_ws;
  auto alloc = [&](size_t bytes)->void*{
    void* r = (void*)p;
    p += (bytes + 255) & ~(size_t)255;
    return r;
  };
  short* gradXb = (short*)alloc((size_t)NVV*NVV*2);        // 32 MB
  short* gradYb = (short*)alloc((size_t)NVV*NVV*2);        // 32 MB
  short* rbfb   = (short*)alloc((size_t)NVV*NGG*2);        // 16 MB  [NV x NG]
  short* rbfTb  = (short*)alloc((size_t)NVV*NGG*2);        // 16 MB  [NG x NV]
  float* part  = (float*)alloc((size_t)2*NSLICE*NVV*DD*4); // 16 MB (16 slices max)
  float* bufA  = (float*)alloc((size_t)NVV*DD*4);          // 1 MB each
  float* bufB  = (float*)alloc((size_t)NVV*DD*4);
  float* xdiff = (float*)alloc((size_t)NVV*DD*4);
  float* tmpg  = (float*)alloc((size_t)NGG*DD*4);          // 0.5 MB each
  float* hg    = (float*)alloc((size_t)NGG*DD*4);
  float* tmp2  = (float*)alloc((size_t)NGG*DD*4);
  float* gx2   = (float*)alloc((size_t)NGG*DD*4);
  float* cs    = (float*)alloc((size_t)KSP*DD*4);
  float* dinv  = (float*)alloc((size_t)NGG*4);
  int*   flg   = (int*)alloc(256);

  // dtype probe first — everything downstream reads the flag
  k_probe<<<1, 64, 0, stream>>>(mass, flg);
  // one-time invariants: bf16 grads, bf16 rbf both layouts (LDS-staged)
  k_cvt<<<NVV*NVV/(256*8), 256, 0, stream>>>(gradX, gradXb, flg);
  k_cvt<<<NVV*NVV/(256*8), 256, 0, stream>>>(gradY, gradYb, flg);
  k_rbf_pre<<<dim3(NVV, NGG/2048), 256, 0, stream>>>(vertices, gpos, rbfb, NGG, flg);
  k_rbf_pre<<<dim3(NGG, NVV/2048), 256, 0, stream>>>(gpos, vertices, rbfTb, NVV, flg);
  k_deginit<<<NGG/256, 256, 0, stream>>>(dinv);
  k_degacc <<<NEDGE/256, 256, 0, stream>>>(ei, dinv);
  k_dinv   <<<NGG/256, 256, 0, stream>>>(dinv);
  k_lin1   <<<NVV*DD/256, 256, 0, stream>>>(surf_x, lin1_w, lin1_b, bufA, flg);

  float* cur = bufA;
  float* alt = bufB;
  for (int b = 0; b < NBLK; b++){
    // spectral projection + diffusion scale
    k_spec_part<<<dim3(KSP, VS), 256, 0, stream>>>(evecs, mass, cur, part, flg);
    k_spec_red<<<KSP*DD/256, 256, 0, stream>>>(part, evals, dtime, b*DD, cs, flg);
    // x_diff = evecs @ cs  (M=NV, K=128)
    k_gemm_mfma<<<dim3(NVV/64,1), 256, 0, stream>>>(evecs, cs, xdiff, NVV, KSP, KSP, flg);
    // gX | gY = {gradX,gradY} @ x_diff — one launch, 16 slices, bf16 A
    k_gemm_grad<<<dim3(NVV/64, 2*NSLICE), 256, 0, stream>>>(gradXb, gradYb, xdiff, part, NVV/NSLICE);
    // fused: split-K sums + gfeat + MLP + residual
    k_tail<<<NVV/4, 256, 0, stream>>>(part, cur, xdiff, A_re, A_im,
                                      mw0, mb0, mw1, mb1, mw2, mb2,
                                      b*DD*DD, b*3*DD*DD, b*DD*DD, b*DD, alt, flg);
    // gx = rbf^T @ mlp_out  (M=NG, K=NV), bf16 A
    k_gemm_bf16<<<dim3(NGG/64,NSLICE_G), 256, 0, stream>>>(rbfTb, alt, part, NGG, NVV, NVV/NSLICE_G);
    // GCN conv1: partial-sum + gemm + bias/dinv init, then edge scatter
    k_gcn1<<<NGG/4, 256, 0, stream>>>(part, gw1, b*DD*DD, dinv, gb1, b*DD, tmpg, hg, flg);
    k_scatter<<<NEDGE*DD/256, 256, 0, stream>>>(ei, dinv, tmpg, hg);
    // GCN conv2: relu + gemm + init, then scatter
    k_gcn2<<<NGG/4, 256, 0, stream>>>(hg, gw2, b*DD*DD, dinv, gb2, b*DD, tmp2, gx2, flg);
    k_scatter<<<NEDGE*DD/256, 256, 0, stream>>>(ei, dinv, tmp2, gx2);
    // diff_x = rbf @ gx2  (M=NV, K=NG), bf16 A
    k_gemm_bf16<<<dim3(NVV/64,NSLICE), 256, 0, stream>>>(rbfb, gx2, part, NVV, NGG, NGG/NSLICE);
    k_reduce<<<NVV*DD/256, 256, 0, stream>>>(part, cur, NVV, NSLICE);
  }
  k_final<<<NVV*COUT/256, 256, 0, stream>>>(cur, last_w, last_b, d_out, flg);
}